// Round 1
// baseline (490.728 us; speedup 1.0000x reference)
//
#include <hip/hip_runtime.h>
#include <math.h>

#define HDIM 64

// One wave (64 lanes) per edge: lane i scatter-adds x[src][i] into aggx[dst][i].
// Lane 0 also counts degree. 80M fp32 atomics total — destinations random over
// 100k vars so per-address contention is ~12.5 over the whole run.
__global__ __launch_bounds__(256) void k_edge(const float* __restrict__ x,
        const int* __restrict__ src, const int* __restrict__ dst,
        float* __restrict__ aggx, float* __restrict__ deg, int E) {
    int w = (int)((blockIdx.x * blockDim.x + threadIdx.x) >> 6);
    int lane = threadIdx.x & 63;
    if (w >= E) return;
    int s = src[w];
    int d = dst[w];
    float v = x[(size_t)s * HDIM + lane];
    atomicAdd(&aggx[(size_t)d * HDIM + lane], v);
    if (lane == 0) atomicAdd(&deg[d], 1.0f);
}

// Wave per variable: mean_x = aggx/(deg+1e-6); h = relu(W @ mean_x + deg/(deg+1e-6)*b);
// LayerNorm via wave butterfly. W stored transposed in LDS with stride 65
// (bank = (j+lane)%32 -> conflict-free); mean_x broadcast via same-address LDS reads.
__global__ __launch_bounds__(256) void k_post(const float* __restrict__ aggx,
        const float* __restrict__ deg, const float* __restrict__ W,
        const float* __restrict__ b, const float* __restrict__ gamma,
        const float* __restrict__ beta, float* __restrict__ out, int num_var) {
    __shared__ float WT[HDIM * 65];
    __shared__ float bs[HDIM], gs[HDIM], bts[HDIM];
    __shared__ float xs[4][HDIM];
    int tid = threadIdx.x;
    for (int k = tid; k < HDIM * HDIM; k += 256) {
        int i = k >> 6, j = k & 63;
        WT[j * 65 + i] = W[k];           // global read coalesced; LDS write ~conflict-free
    }
    if (tid < HDIM) { bs[tid] = b[tid]; gs[tid] = gamma[tid]; bts[tid] = beta[tid]; }
    __syncthreads();

    int wv = tid >> 6, lane = tid & 63;
    int gw = blockIdx.x * 4 + wv;
    int nw = gridDim.x * 4;
    int iters = (num_var + nw - 1) / nw;   // uniform trip count -> __syncthreads legal
    for (int it = 0; it < iters; ++it) {
        int v = gw + it * nw;
        float mx = 0.0f, scale_b = 0.0f;
        if (v < num_var) {
            float dv = deg[v];
            float inv = 1.0f / (dv + 1e-6f);
            mx = aggx[(size_t)v * HDIM + lane] * inv;
            scale_b = dv * inv;
        }
        xs[wv][lane] = mx;
        __syncthreads();
        float acc = bs[lane] * scale_b;
        #pragma unroll
        for (int j = 0; j < HDIM; ++j) {
            acc += WT[j * 65 + lane] * xs[wv][j];   // WT conflict-free, xs broadcast
        }
        __syncthreads();   // before next iteration's xs write
        if (v < num_var) {
            float h = fmaxf(acc, 0.0f);
            float s1 = h, s2 = h * h;
            #pragma unroll
            for (int off = 32; off > 0; off >>= 1) {
                s1 += __shfl_xor(s1, off, 64);
                s2 += __shfl_xor(s2, off, 64);
            }
            float mu = s1 * (1.0f / 64.0f);
            float var = s2 * (1.0f / 64.0f) - mu * mu;
            var = fmaxf(var, 0.0f);
            float r = rsqrtf(var + 1e-5f);
            out[(size_t)v * HDIM + lane] = (h - mu) * r * gs[lane] + bts[lane];
        }
    }
}

extern "C" void kernel_launch(void* const* d_in, const int* in_sizes, int n_in,
                              void* d_out, int out_size, void* d_ws, size_t ws_size,
                              hipStream_t stream) {
    const float* x_con = (const float*)d_in[0];
    const int*   src   = (const int*)d_in[1];
    const int*   dst   = (const int*)d_in[2];
    // d_in[3] is num_var on device; derive from out_size instead (out = num_var*H)
    const float* W     = (const float*)d_in[4];
    const float* b     = (const float*)d_in[5];
    const float* gamma = (const float*)d_in[6];
    const float* beta  = (const float*)d_in[7];
    float* out = (float*)d_out;

    int E = in_sizes[1];
    int num_var = out_size / HDIM;

    float* aggx = (float*)d_ws;                        // num_var*64 floats
    float* deg  = aggx + (size_t)num_var * HDIM;       // num_var floats

    size_t zero_bytes = ((size_t)num_var * HDIM + num_var) * sizeof(float);
    hipMemsetAsync(d_ws, 0, zero_bytes, stream);

    // edge scatter: one wave per edge
    {
        long long threads = (long long)E * 64;
        int block = 256;
        long long grid = (threads + block - 1) / block;
        k_edge<<<(dim3)(unsigned)grid, block, 0, stream>>>(x_con, src, dst, aggx, deg, E);
    }

    // per-variable linear + relu + layernorm
    {
        int block = 256;
        int grid = 2048;   // 8192 waves -> ~13 vars per wave
        k_post<<<grid, block, 0, stream>>>(aggx, deg, W, b, gamma, beta, out, num_var);
    }
}

// Round 2
// 413.461 us; speedup vs baseline: 1.1869x; 1.1869x over previous
//
#include <hip/hip_runtime.h>
#include <math.h>

#define HDIM 64

// Step 1: integer degree histogram. 1.25M int atomics over 100k counters.
__global__ __launch_bounds__(256) void k_hist(const int* __restrict__ dst,
                                              int* __restrict__ cnt, int E) {
    int e = blockIdx.x * blockDim.x + threadIdx.x;
    if (e < E) atomicAdd(&cnt[dst[e]], 1);
}

// Step 2: allocate disjoint segments. We don't need an ordered prefix sum —
// only disjoint [base, base+cnt) ranges — so a single global cursor with
// wave-aggregated atomics suffices (1564 wave-level atomics to one address).
// cnt[v] is rewritten as the running write-cursor for step 3; offs[v] keeps
// the segment start.
__global__ __launch_bounds__(256) void k_alloc(int* __restrict__ cnt,
        int* __restrict__ offs, int* __restrict__ cursor, int num_var) {
    int v = blockIdx.x * blockDim.x + threadIdx.x;
    int lane = threadIdx.x & 63;
    int c = (v < num_var) ? cnt[v] : 0;
    int pre = c;                       // inclusive wave prefix sum
    #pragma unroll
    for (int off = 1; off < 64; off <<= 1) {
        int t = __shfl_up(pre, off, 64);
        if (lane >= off) pre += t;
    }
    int total = __shfl(pre, 63, 64);
    int base = 0;
    if (lane == 63) base = atomicAdd(cursor, total);
    base = __shfl(base, 63, 64);
    int my = base + pre - c;           // exclusive position
    if (v < num_var) { offs[v] = my; cnt[v] = my; }
}

// Step 3: counting-sort scatter of src indices into per-dst segments.
__global__ __launch_bounds__(256) void k_scatter(const int* __restrict__ src,
        const int* __restrict__ dst, int* __restrict__ cur,
        int* __restrict__ sorted_src, int E) {
    int e = blockIdx.x * blockDim.x + threadIdx.x;
    if (e < E) {
        int p = atomicAdd(&cur[dst[e]], 1);
        sorted_src[p] = src[e];
    }
}

// Step 4: fused segmented-sum + linear + ReLU + LayerNorm.
// One wave per variable. Lane i owns output component i:
//   - W row i cached in 64 VGPRs (loaded once per wave, L2-hot)
//   - neighbor idx chunk staged in wave-private LDS, read back as broadcast
//     ds_read_b128 (4 indices per LDS op)
//   - mean vector broadcast the same way (1 ds_write + 16 ds_read_b128)
// No __syncthreads needed: LDS buffers are wave-private; DS ops from one wave
// complete in program order. wave_barrier() pins compiler ordering.
__global__ __launch_bounds__(256) void k_final(const float* __restrict__ x,
        const int* __restrict__ sorted_src, const int* __restrict__ offs,
        const int* __restrict__ ends, const float* __restrict__ W,
        const float* __restrict__ b, const float* __restrict__ gamma,
        const float* __restrict__ beta, float* __restrict__ out, int num_var) {
    __shared__ __align__(16) float fbuf[4][HDIM];
    __shared__ __align__(16) int   ibuf[4][HDIM];
    int tid = threadIdx.x, wv = tid >> 6, lane = tid & 63;

    float4 wreg[16];                   // W[lane][0..63]
    #pragma unroll
    for (int t = 0; t < 16; ++t) wreg[t] = ((const float4*)(W + lane * HDIM))[t];
    float b_l = b[lane], g_l = gamma[lane], bt_l = beta[lane];

    int gw = blockIdx.x * 4 + wv, nw = gridDim.x * 4;
    for (int v = gw; v < num_var; v += nw) {
        int start = offs[v], end = ends[v];
        int deg = end - start;
        float sum = 0.0f;
        for (int j0 = start; j0 < end; j0 += 64) {
            int m = end - j0; if (m > 64) m = 64;
            ibuf[wv][lane] = (lane < m) ? sorted_src[j0 + lane] : 0;
            __builtin_amdgcn_wave_barrier();
            for (int t = 0; t < m; t += 4) {        // m is wave-uniform
                int4 s4 = *((const int4*)&ibuf[wv][t]);   // broadcast read
                sum += x[(size_t)s4.x * HDIM + lane];
                if (t + 1 < m) sum += x[(size_t)s4.y * HDIM + lane];
                if (t + 2 < m) sum += x[(size_t)s4.z * HDIM + lane];
                if (t + 3 < m) sum += x[(size_t)s4.w * HDIM + lane];
            }
            __builtin_amdgcn_wave_barrier();
        }
        float dv = (float)deg;
        float inv = 1.0f / (dv + 1e-6f);
        float mean = sum * inv;
        fbuf[wv][lane] = mean;
        __builtin_amdgcn_wave_barrier();
        float acc = b_l * (dv * inv);              // W @ mean + deg/(deg+eps) * b
        #pragma unroll
        for (int t = 0; t < 16; ++t) {
            float4 m4 = *((const float4*)&fbuf[wv][4 * t]);  // broadcast read
            acc = fmaf(wreg[t].x, m4.x, acc);
            acc = fmaf(wreg[t].y, m4.y, acc);
            acc = fmaf(wreg[t].z, m4.z, acc);
            acc = fmaf(wreg[t].w, m4.w, acc);
        }
        __builtin_amdgcn_wave_barrier();
        float h = fmaxf(acc, 0.0f);
        float s1 = h, s2 = h * h;
        #pragma unroll
        for (int off = 32; off > 0; off >>= 1) {
            s1 += __shfl_xor(s1, off, 64);
            s2 += __shfl_xor(s2, off, 64);
        }
        float mu = s1 * (1.0f / 64.0f);
        float var = fmaxf(s2 * (1.0f / 64.0f) - mu * mu, 0.0f);
        float r = rsqrtf(var + 1e-5f);
        out[(size_t)v * HDIM + lane] = (h - mu) * r * g_l + bt_l;
    }
}

extern "C" void kernel_launch(void* const* d_in, const int* in_sizes, int n_in,
                              void* d_out, int out_size, void* d_ws, size_t ws_size,
                              hipStream_t stream) {
    const float* x_con = (const float*)d_in[0];
    const int*   src   = (const int*)d_in[1];
    const int*   dst   = (const int*)d_in[2];
    const float* W     = (const float*)d_in[4];
    const float* b     = (const float*)d_in[5];
    const float* gamma = (const float*)d_in[6];
    const float* beta  = (const float*)d_in[7];
    float* out = (float*)d_out;

    int E = in_sizes[1];
    int num_var = out_size / HDIM;

    // ws layout: [cnt: num_var][cursor: 1][offs: num_var][sorted_src: E]
    int* cnt        = (int*)d_ws;
    int* cursor     = cnt + num_var;
    int* offs       = cursor + 1;
    int* sorted_src = offs + num_var;

    hipMemsetAsync(d_ws, 0, (size_t)(num_var + 1) * sizeof(int), stream);

    int eb = (E + 255) / 256;
    int vb = (num_var + 255) / 256;
    k_hist<<<eb, 256, 0, stream>>>(dst, cnt, E);
    k_alloc<<<vb, 256, 0, stream>>>(cnt, offs, cursor, num_var);
    k_scatter<<<eb, 256, 0, stream>>>(src, dst, cnt, sorted_src, E);
    // after scatter, cnt[v] == segment end
    k_final<<<2048, 256, 0, stream>>>(x_con, sorted_src, offs, cnt, W, b,
                                      gamma, beta, out, num_var);
}

// Round 3
// 204.708 us; speedup vs baseline: 2.3972x; 2.0198x over previous
//
#include <hip/hip_runtime.h>
#include <math.h>

#define HDIM 64

// ---------------------------------------------------------------------------
// Pass 1: partition edges into 512-var buckets (bucket = dst >> 9).
// Each block stages 4096 edges: LDS histogram -> one returning global atomic
// per (block, bucket) on a padded (64B-strided) cursor -> LDS-ordered staging
// -> coalesced global writes of (src,dst) pairs into per-bucket regions.
// This replaces 2.5M contended global atomics with ~78k padded ones.
// ---------------------------------------------------------------------------
__global__ __launch_bounds__(256) void k_partition(
        const int* __restrict__ src, const int* __restrict__ dst,
        int2* __restrict__ pairs, int* __restrict__ bcur,
        int E, int NB, int CAP) {
    __shared__ int hist[256], incl[256], exs[256], gb[256], cur2[256];
    __shared__ int2 pairbuf[4096];          // 32 KB
    __shared__ unsigned char bkt[4096];     // 4 KB (byte writes are safe on DS)
    int t = threadIdx.x;
    int e0 = blockIdx.x << 12;
    int nE = E - e0; if (nE > 4096) nE = 4096;

    hist[t] = 0;
    __syncthreads();

    int2 pr[16];                            // keep edges in VGPRs (1 global read)
    #pragma unroll
    for (int k = 0; k < 16; ++k) {
        int e = e0 + (k << 8) + t;
        if (e < E) {
            pr[k].x = src[e];
            pr[k].y = dst[e];
            atomicAdd(&hist[pr[k].y >> 9], 1);
        }
    }
    __syncthreads();

    int h = hist[t];
    incl[t] = h;
    __syncthreads();
    for (int off = 1; off < 256; off <<= 1) {   // Hillis-Steele inclusive scan
        int val = (t >= off) ? incl[t - off] : 0;
        __syncthreads();
        incl[t] += val;
        __syncthreads();
    }
    exs[t] = incl[t] - h;                       // exclusive
    cur2[t] = 0;
    gb[t] = (t < NB) ? (t * CAP + atomicAdd(&bcur[t << 4], h)) : 0;
    __syncthreads();

    #pragma unroll
    for (int k = 0; k < 16; ++k) {
        int e = e0 + (k << 8) + t;
        if (e < E) {
            int bb = pr[k].y >> 9;
            int r = atomicAdd(&cur2[bb], 1);    // LDS atomic, order irrelevant
            int slot = exs[bb] + r;
            pairbuf[slot] = pr[k];
            bkt[slot] = (unsigned char)bb;
        }
    }
    __syncthreads();

    #pragma unroll
    for (int k = 0; k < 16; ++k) {
        int slot = (k << 8) + t;
        if (slot < nE) {
            int bb = bkt[slot];
            int g = gb[bb] + (slot - exs[bb]);
            if (g < (bb + 1) * CAP)             // overflow guard (never for real data)
                pairs[g] = pairbuf[slot];       // coalesced runs (~16 pairs/bucket)
        }
    }
}

// ---------------------------------------------------------------------------
// Pass 2: one block per bucket — exact counting sort of ~6400 edges over its
// 512 vars entirely in LDS. Emits sorted_src, absolute offs[v], deg[v].
// ---------------------------------------------------------------------------
__global__ __launch_bounds__(256) void k_bucket_sort(
        const int2* __restrict__ pairs, const int* __restrict__ bcur,
        int* __restrict__ sorted_src, int* __restrict__ offs,
        int* __restrict__ degA, int V, int CAP) {
    __shared__ int vcnt[512], vcur[512], sc[256];
    int b = blockIdx.x, t = threadIdx.x;
    int base = b * CAP;
    int cnt = bcur[b << 4]; if (cnt > CAP) cnt = CAP;

    vcnt[t] = 0; vcnt[t + 256] = 0;
    __syncthreads();
    for (int e = t; e < cnt; e += 256) {
        int2 p = pairs[base + e];
        atomicAdd(&vcnt[p.y & 511], 1);
    }
    __syncthreads();

    int a0 = vcnt[2 * t], a1 = vcnt[2 * t + 1];
    int s = a0 + a1;
    sc[t] = s;
    __syncthreads();
    for (int off = 1; off < 256; off <<= 1) {
        int val = (t >= off) ? sc[t - off] : 0;
        __syncthreads();
        sc[t] += val;
        __syncthreads();
    }
    int ex = sc[t] - s;
    int v0 = (b << 9) + 2 * t;
    if (v0 < V)     { offs[v0]     = base + ex;      degA[v0]     = a0; }
    if (v0 + 1 < V) { offs[v0 + 1] = base + ex + a0; degA[v0 + 1] = a1; }
    vcur[2 * t] = ex;
    vcur[2 * t + 1] = ex + a0;
    __syncthreads();
    for (int e = t; e < cnt; e += 256) {
        int2 p = pairs[base + e];
        int r = atomicAdd(&vcur[p.y & 511], 1);
        sorted_src[base + r] = p.x;              // writes stay in 25 KB region
    }
}

// ---------------------------------------------------------------------------
// Pass 3: fused segmented-sum + linear + ReLU + LayerNorm. One wave per var.
// Lane layout: quarter q = lane>>4 owns row-slot q of each 4-row group; group
// col c = lane&15 owns columns 4c..4c+3. Gather: each quarter reads one full
// x row per float4 instruction (wave = 4 rows/instr). Quarter combine = 8
// shfls. Matvec: quarter q computes outputs 16q..16q+15 from coalesced W row
// slices; a 4-step in-register butterfly transpose-reduce lands output i on
// lane i exactly. No LDS at all.
// ---------------------------------------------------------------------------
__global__ __launch_bounds__(256) void k_final(
        const float* __restrict__ x, const int* __restrict__ sorted_src,
        const int* __restrict__ offs, const int* __restrict__ degA,
        const float* __restrict__ W, const float* __restrict__ b,
        const float* __restrict__ gamma, const float* __restrict__ beta,
        float* __restrict__ out, int V) {
    int tid = threadIdx.x;
    int wv = tid >> 6, lane = tid & 63;
    int q = lane >> 4, c = lane & 15;
    int v = blockIdx.x * 4 + wv;
    if (v >= V) return;                         // wave-uniform exit

    int start = offs[v];
    int dg = degA[v];

    float ax = 0.0f, ay = 0.0f, az = 0.0f, aw = 0.0f;
    for (int t = 0; t < dg; t += 16) {          // 16 rows in flight per iter
        #pragma unroll
        for (int k = 0; k < 4; ++k) {
            int ii = t + (k << 2) + q;
            if (ii < dg) {
                int s = sorted_src[start + ii];             // uniform in quarter
                const float4 xv = *(const float4*)(x + ((size_t)s << 6) + (c << 2));
                ax += xv.x; ay += xv.y; az += xv.z; aw += xv.w;
            }
        }
    }
    // combine the 4 quarters -> every lane holds full column sums for 4c..4c+3
    ax += __shfl_xor(ax, 16, 64); ax += __shfl_xor(ax, 32, 64);
    ay += __shfl_xor(ay, 16, 64); ay += __shfl_xor(ay, 32, 64);
    az += __shfl_xor(az, 16, 64); az += __shfl_xor(az, 32, 64);
    aw += __shfl_xor(aw, 16, 64); aw += __shfl_xor(aw, 32, 64);

    // partial dots: p[i] = W[16q+i][4c..4c+3] . sum4   (quarter-coalesced W reads)
    float p[16];
    #pragma unroll
    for (int i = 0; i < 16; ++i) {
        const float4 w4 = *(const float4*)(W + ((((q << 4) + i) << 6)) + (c << 2));
        p[i] = fmaf(w4.x, ax, fmaf(w4.y, ay, fmaf(w4.z, az, w4.w * aw)));
    }
    // butterfly transpose-reduce across the 16 lanes of the quarter:
    // after 4 steps lane (q,c) holds out[16q+c] = lane's own component.
    {
        int hi = c & 8;
        #pragma unroll
        for (int k = 0; k < 8; ++k) {
            float keep = hi ? p[k + 8] : p[k];
            float give = hi ? p[k] : p[k + 8];
            p[k] = keep + __shfl_xor(give, 8, 64);
        }
    }
    {
        int hi = c & 4;
        #pragma unroll
        for (int k = 0; k < 4; ++k) {
            float keep = hi ? p[k + 4] : p[k];
            float give = hi ? p[k] : p[k + 4];
            p[k] = keep + __shfl_xor(give, 4, 64);
        }
    }
    {
        int hi = c & 2;
        #pragma unroll
        for (int k = 0; k < 2; ++k) {
            float keep = hi ? p[k + 2] : p[k];
            float give = hi ? p[k] : p[k + 2];
            p[k] = keep + __shfl_xor(give, 2, 64);
        }
    }
    {
        int hi = c & 1;
        float keep = hi ? p[1] : p[0];
        float give = hi ? p[0] : p[1];
        p[0] = keep + __shfl_xor(give, 1, 64);
    }

    float dv = (float)dg;
    float inv = 1.0f / (dv + 1e-6f);
    float acc = (p[0] + b[lane] * dv) * inv;    // (W@sum + deg*b)/(deg+eps)
    float h = fmaxf(acc, 0.0f);

    float s1 = h, s2 = h * h;
    #pragma unroll
    for (int off = 32; off > 0; off >>= 1) {
        s1 += __shfl_xor(s1, off, 64);
        s2 += __shfl_xor(s2, off, 64);
    }
    float mu = s1 * (1.0f / 64.0f);
    float var = fmaxf(s2 * (1.0f / 64.0f) - mu * mu, 0.0f);
    float r = rsqrtf(var + 1e-5f);
    out[((size_t)v << 6) + lane] = (h - mu) * r * gamma[lane] + beta[lane];
}

extern "C" void kernel_launch(void* const* d_in, const int* in_sizes, int n_in,
                              void* d_out, int out_size, void* d_ws, size_t ws_size,
                              hipStream_t stream) {
    const float* x_con = (const float*)d_in[0];
    const int*   src   = (const int*)d_in[1];
    const int*   dst   = (const int*)d_in[2];
    const float* W     = (const float*)d_in[4];
    const float* b     = (const float*)d_in[5];
    const float* gamma = (const float*)d_in[6];
    const float* beta  = (const float*)d_in[7];
    float* out = (float*)d_out;

    int E = in_sizes[1];
    int V = out_size / HDIM;

    int NB = (V + 511) >> 9;                    // buckets of 512 vars (<=256)
    int avg = (E + NB - 1) / NB;
    int CAP = avg + (avg >> 3) + 768;           // ~19 sigma headroom
    CAP = (CAP + 7) & ~7;

    // ws layout: [pairs: NB*CAP int2][bcur: 4096 int padded][offs: V][deg: V][sorted_src: NB*CAP]
    int2* pairs = (int2*)d_ws;
    int*  bcur  = (int*)(pairs + (size_t)NB * CAP);
    int*  offs  = bcur + 4096;
    int*  degA  = offs + V;
    int*  srt   = degA + V;

    hipMemsetAsync(bcur, 0, 4096 * sizeof(int), stream);
    k_partition<<<(E + 4095) / 4096, 256, 0, stream>>>(src, dst, pairs, bcur, E, NB, CAP);
    k_bucket_sort<<<NB, 256, 0, stream>>>(pairs, bcur, srt, offs, degA, V, CAP);
    k_final<<<(V + 3) / 4, 256, 0, stream>>>(x_con, srt, offs, degA, W, b, gamma, beta, out, V);
}